// Round 5
// baseline (1191.304 us; speedup 1.0000x reference)
//
#include <hip/hip_runtime.h>
#include <math.h>

// Model_13486197309850: GCN(+self-loop sym-norm, segment_max) || 2-layer BiLSTM -> MLP head.
// R3->R4 (resubmitted r5; r4 bench never ran - GPU acquisition timeout):
//   lstm_rec spill fix + LDS conflict fix.
//   - __launch_bounds__(512,1): r3's (512,2) produced VGPR=88 => the 128 weight floats
//     spilled to scratch (cap was 128 under min-blocks semantics). With ,1 the cap is
//     >=256 and w[4][8] float4s (+pins) stay resident.
//   - hbuf rotated layout: slice ks group g at phys float4 ks*8+((g+ks)&7); at unrolled
//     step p the four ks lanes hit banks 4*((p+ks)&7) -- distinct -> conflict-free
//     (r3 had 1.7e7 conflicts from stride-32 slices).
// GEMMs (bf16 MFMA 3-term hi/lo split) unchanged from r2.

namespace {

constexpr int kN  = 32768;
constexpr int kB  = 128;
constexpr int kL  = 256;
constexpr int kF  = 768;
constexpr int kNH = 256;
constexpr int kH  = 128;
constexpr int kE  = 524288;

typedef __attribute__((ext_vector_type(8))) short bf16x8;
typedef __attribute__((ext_vector_type(4))) float f32x4;
typedef __attribute__((address_space(3))) unsigned int lds_u32;
typedef __attribute__((address_space(1))) unsigned int glb_u32;

__device__ __forceinline__ float sigf(float x)  { return 1.f / (1.f + __expf(-x)); }
__device__ __forceinline__ float tanh_f(float x){ return 1.f - 2.f / (1.f + __expf(2.f * x)); }

__device__ __forceinline__ unsigned short f2bf(float f) {
  unsigned int u = __float_as_uint(f);
  u = u + 0x7fffu + ((u >> 16) & 1u);   // RNE to bf16
  return (unsigned short)(u >> 16);
}
__device__ __forceinline__ float bf2f(unsigned short h) {
  return __uint_as_float((unsigned int)h << 16);
}

// ---------------- GCN: degree count / scan / CSR fill ----------------

__global__ void count_edges(const int* __restrict__ col, int* __restrict__ cnt) {
  int e = blockIdx.x * 256 + threadIdx.x;
  if (e < kE) atomicAdd(&cnt[col[e]], 1);
}

__global__ void scan_dinv(const int* __restrict__ cnt, int* __restrict__ offs,
                          int* __restrict__ cursor, float* __restrict__ dinv) {
  __shared__ int part[1024];
  int t = threadIdx.x;
  int base = t * 32;
  int loc[32];
  int s = 0;
#pragma unroll
  for (int i = 0; i < 32; i++) { loc[i] = cnt[base + i]; s += loc[i]; }
  part[t] = s;
  __syncthreads();
  for (int d = 1; d < 1024; d <<= 1) {
    int v = part[t];
    int add = (t >= d) ? part[t - d] : 0;
    __syncthreads();
    part[t] = v + add;
    __syncthreads();
  }
  int run = (t == 0) ? 0 : part[t - 1];
#pragma unroll
  for (int i = 0; i < 32; i++) {
    offs[base + i] = run;
    cursor[base + i] = run;
    dinv[base + i] = rsqrtf((float)(loc[i] + 1));
    run += loc[i];
  }
  if (t == 1023) offs[kN] = run;
}

__global__ void fill_csr(const int* __restrict__ row, const int* __restrict__ col,
                         int* __restrict__ cursor, int* __restrict__ elist) {
  int e = blockIdx.x * 256 + threadIdx.x;
  if (e < kE) {
    int c = col[e];
    int p = atomicAdd(&cursor[c], 1);
    elist[p] = row[e];
  }
}

// ---------------- weight conversion: fp32 -> (N,K) bf16 hi/lo ----------------

__global__ void convert_bt(const float* __restrict__ W, unsigned short* __restrict__ hi,
                           unsigned short* __restrict__ lo, int Nn, int Kk, int trans) {
  int idx = blockIdx.x * 256 + threadIdx.x;
  if (idx >= Nn * Kk) return;
  int n = idx / Kk, k = idx - n * Kk;
  float f = trans ? W[(size_t)k * Nn + n] : W[idx];
  unsigned short h = f2bf(f);
  hi[idx] = h;
  lo[idx] = f2bf(f - bf2f(h));
}

// ---------------- MFMA GEMM, 3-term hi/lo split (unchanged from r2) ----------------

__global__ __launch_bounds__(256, 2) void gemm3(const float* __restrict__ A,
                                                const unsigned short* __restrict__ Bhi,
                                                const unsigned short* __restrict__ Blo,
                                                float* __restrict__ C,
                                                int M, int N, int K) {
  __shared__ __align__(16) char lds[32768];
  const int tid = threadIdx.x;
  const int lane = tid & 63;
  const int w = tid >> 6, wr = w >> 1, wc = w & 1;
  const int m0 = blockIdx.y * 128, n0 = blockIdx.x * 128;

  f32x4 acc[4][4];
#pragma unroll
  for (int i = 0; i < 4; i++)
#pragma unroll
    for (int j = 0; j < 4; j++) acc[i][j] = (f32x4)0.f;

  const float* aptr[4];
  int aoff[4];
#pragma unroll
  for (int i = 0; i < 4; i++) {
    int f = tid + i * 256;
    int row = f >> 3, kq4 = f & 7;
    aptr[i] = A + (size_t)(m0 + row) * K + kq4 * 4;
    int sub = row >> 4, r = row & 15, q = kq4 >> 1, hs = kq4 & 1;
    aoff[i] = sub * 1024 + (q * 16 + r) * 16 + hs * 8;
  }
  const unsigned short* bsrc[4];
  int boff[4];
#pragma unroll
  for (int j = 0; j < 4; j++) {
    int id = w * 4 + j;
    int isLo = id >> 3, sub = id & 7;
    const unsigned short* Bp = isLo ? Blo : Bhi;
    bsrc[j] = Bp + (size_t)(n0 + sub * 16 + (lane & 15)) * K + (lane >> 4) * 8;
    boff[j] = 16384 + isLo * 8192 + sub * 1024;
  }

  for (int k0 = 0; k0 < K; k0 += 32) {
#pragma unroll
    for (int j = 0; j < 4; j++) {
      __builtin_amdgcn_global_load_lds((const glb_u32*)bsrc[j],
                                       (lds_u32*)(lds + boff[j]), 16, 0, 0);
      bsrc[j] += 32;
    }
#pragma unroll
    for (int i = 0; i < 4; i++) {
      f32x4 v = *(const f32x4*)(aptr[i]);
      aptr[i] += 32;
      unsigned short h0 = f2bf(v.x), h1 = f2bf(v.y), h2 = f2bf(v.z), h3 = f2bf(v.w);
      unsigned short g0 = f2bf(v.x - bf2f(h0)), g1 = f2bf(v.y - bf2f(h1));
      unsigned short g2 = f2bf(v.z - bf2f(h2)), g3 = f2bf(v.w - bf2f(h3));
      uint2 hv, lv;
      hv.x = (unsigned int)h0 | ((unsigned int)h1 << 16);
      hv.y = (unsigned int)h2 | ((unsigned int)h3 << 16);
      lv.x = (unsigned int)g0 | ((unsigned int)g1 << 16);
      lv.y = (unsigned int)g2 | ((unsigned int)g3 << 16);
      *(uint2*)(lds + aoff[i]) = hv;
      *(uint2*)(lds + aoff[i] + 8192) = lv;
    }
    __syncthreads();

    const bf16x8* L = (const bf16x8*)lds;
    bf16x8 ah[4], al[4], bh[4], bl[4];
#pragma unroll
    for (int m = 0; m < 4; m++) {
      ah[m] = L[(wr * 4 + m) * 64 + lane];
      al[m] = L[512 + (wr * 4 + m) * 64 + lane];
    }
#pragma unroll
    for (int n = 0; n < 4; n++) {
      bh[n] = L[1024 + (wc * 4 + n) * 64 + lane];
      bl[n] = L[1536 + (wc * 4 + n) * 64 + lane];
    }
#pragma unroll
    for (int m = 0; m < 4; m++)
#pragma unroll
      for (int n = 0; n < 4; n++) {
        acc[m][n] = __builtin_amdgcn_mfma_f32_16x16x32_bf16(ah[m], bh[n], acc[m][n], 0, 0, 0);
        acc[m][n] = __builtin_amdgcn_mfma_f32_16x16x32_bf16(ah[m], bl[n], acc[m][n], 0, 0, 0);
        acc[m][n] = __builtin_amdgcn_mfma_f32_16x16x32_bf16(al[m], bh[n], acc[m][n], 0, 0, 0);
      }
    __syncthreads();
  }

#pragma unroll
  for (int m = 0; m < 4; m++)
#pragma unroll
    for (int n = 0; n < 4; n++) {
      int r0 = m0 + wr * 64 + m * 16 + (lane >> 4) * 4;
      int cc = n0 + wc * 64 + n * 16 + (lane & 15);
#pragma unroll
      for (int j = 0; j < 4; j++)
        C[(size_t)(r0 + j) * N + cc] = acc[m][n][j];
    }
}

// ---------------- GCN gather + relu(+bias), then segment max ----------------

__global__ __launch_bounds__(256) void gcn_gather(const float* __restrict__ hg,
                                                  const int* __restrict__ offs,
                                                  const int* __restrict__ elist,
                                                  const float* __restrict__ dinv,
                                                  const float* __restrict__ bgcn,
                                                  float* __restrict__ out) {
  int n = blockIdx.x, j = threadIdx.x;
  float di = dinv[n];
  float acc = hg[(size_t)n * kNH + j] * (di * di);
  int s = offs[n], e = offs[n + 1];
  int p = s;
  for (; p + 4 <= e; p += 4) {
    int r0 = elist[p], r1 = elist[p + 1], r2 = elist[p + 2], r3 = elist[p + 3];
    float w0 = di * dinv[r0], w1 = di * dinv[r1], w2 = di * dinv[r2], w3 = di * dinv[r3];
    float v0 = hg[(size_t)r0 * kNH + j], v1 = hg[(size_t)r1 * kNH + j];
    float v2 = hg[(size_t)r2 * kNH + j], v3 = hg[(size_t)r3 * kNH + j];
    acc = fmaf(v0, w0, acc); acc = fmaf(v1, w1, acc);
    acc = fmaf(v2, w2, acc); acc = fmaf(v3, w3, acc);
  }
  for (; p < e; p++) {
    int r = elist[p];
    acc = fmaf(hg[(size_t)r * kNH + j], di * dinv[r], acc);
  }
  acc += bgcn[j];
  out[(size_t)n * kNH + j] = fmaxf(acc, 0.f);
}

__global__ __launch_bounds__(256) void segmax(const float* __restrict__ xg_full,
                                              float* __restrict__ x_graph) {
  int g = blockIdx.x, j = threadIdx.x;
  const float* base = xg_full + (size_t)g * kL * kNH + j;
  float m0 = -1e30f, m1 = -1e30f, m2 = -1e30f, m3 = -1e30f;
  for (int t = 0; t < kL; t += 4) {
    m0 = fmaxf(m0, base[(size_t)(t + 0) * kNH]);
    m1 = fmaxf(m1, base[(size_t)(t + 1) * kNH]);
    m2 = fmaxf(m2, base[(size_t)(t + 2) * kNH]);
    m3 = fmaxf(m3, base[(size_t)(t + 3) * kNH]);
  }
  x_graph[g * kNH + j] = fmaxf(fmaxf(m0, m1), fmaxf(m2, m3));
}

// ---------------- LSTM recurrence: quad k-split, resident weights ----------------
// 512 threads: j = t>>2 (h-unit), ks = t&3 (k-slice of 32).
// Thread holds w[4][8] float4 (gates i,f,g,o of unit j, k in [32ks,32ks+32)).
// hbuf rotated layout: logical float l (slice ksl=l>>5, group g=(l>>2)&7, elem e=l&3)
//   stored at phys float (ksl*8 + ((g+ksl)&7))*4 + e. Read step p: lane ks reads
//   phys group ks*8+((p+ks)&7) == logical group p -> banks 4*((p+ks)&7), distinct.
__global__ __launch_bounds__(512, 1) void lstm_rec(const float* __restrict__ Z, int zstride,
                                                   const float* __restrict__ Whh2,
                                                   const float* __restrict__ bias2,
                                                   float* __restrict__ Y0,
                                                   float* __restrict__ hfin, int mode) {
  __shared__ __align__(16) float hbuf[2][kH];
  int b, dir;
  if (mode == 0) { dir = blockIdx.x >> 7; b = blockIdx.x & 127; }
  else           { dir = 1;               b = blockIdx.x; }
  const bool rev = (dir == 1);
  const int t0 = threadIdx.x;
  const int j = t0 >> 2;
  const int ks = t0 & 3;

  float4 w[4][8];
  {
    const float* wb = Whh2 + (size_t)dir * 512 * kH + (size_t)j * kH + ks * 32;
#pragma unroll
    for (int q = 0; q < 4; q++) {
      const float* wr = wb + (size_t)q * kH * kH;  // gate q row = q*128 + j
#pragma unroll
      for (int kk = 0; kk < 8; kk++) w[q][kk] = *(const float4*)(wr + kk * 4);
    }
  }
#pragma unroll
  for (int q = 0; q < 4; q++)
#pragma unroll
    for (int kk = 0; kk < 8; kk++) {
      asm volatile("" : "+v"(w[q][kk].x), "+v"(w[q][kk].y),
                        "+v"(w[q][kk].z), "+v"(w[q][kk].w));
    }

  const float bg = bias2[dir * 512 + ks * kH + j];
  const int zcol = (mode == 0) ? dir * 512 : 0;
  float c = 0.f, hn = 0.f;

  // phys index of logical h[j] (for the single-float state writes)
  const int jph = ((j >> 5) * 8 + ((((j >> 2) & 7) + (j >> 5)) & 7)) * 4 + (j & 3);

  if (t0 < kH) hbuf[0][t0] = 0.f;  // all-zero: layout-agnostic

  const float* zp = Z + (size_t)(b * kL + (rev ? kL - 1 : 0)) * zstride + zcol + ks * kH + j;
  const long zinc = rev ? -(long)zstride : (long)zstride;
  float zt = *zp;
  __syncthreads();

  for (int t = 0; t < kL; t++) {
    const int tt = rev ? (kL - 1 - t) : t;
    float znext = 0.f;
    if (t < kL - 1) znext = zp[zinc];
    zp += zinc;
    const int cur = t & 1;

    const float4* hb = (const float4*)hbuf[cur];
    float a0 = 0.f, a1 = 0.f, a2 = 0.f, a3 = 0.f;
#pragma unroll
    for (int p = 0; p < 8; p++) {
      float4 h4 = hb[ks * 8 + ((p + ks) & 7)];  // logical group p, conflict-free
      a0 = fmaf(w[0][p].x, h4.x, a0); a0 = fmaf(w[0][p].y, h4.y, a0);
      a0 = fmaf(w[0][p].z, h4.z, a0); a0 = fmaf(w[0][p].w, h4.w, a0);
      a1 = fmaf(w[1][p].x, h4.x, a1); a1 = fmaf(w[1][p].y, h4.y, a1);
      a1 = fmaf(w[1][p].z, h4.z, a1); a1 = fmaf(w[1][p].w, h4.w, a1);
      a2 = fmaf(w[2][p].x, h4.x, a2); a2 = fmaf(w[2][p].y, h4.y, a2);
      a2 = fmaf(w[2][p].z, h4.z, a2); a2 = fmaf(w[2][p].w, h4.w, a2);
      a3 = fmaf(w[3][p].x, h4.x, a3); a3 = fmaf(w[3][p].y, h4.y, a3);
      a3 = fmaf(w[3][p].z, h4.z, a3); a3 = fmaf(w[3][p].w, h4.w, a3);
    }
    const float zb = zt + bg;
    a0 += (ks == 0) ? zb : 0.f;
    a1 += (ks == 1) ? zb : 0.f;
    a2 += (ks == 2) ? zb : 0.f;
    a3 += (ks == 3) ? zb : 0.f;
    a0 += __shfl_xor(a0, 1); a1 += __shfl_xor(a1, 1);
    a2 += __shfl_xor(a2, 1); a3 += __shfl_xor(a3, 1);
    a0 += __shfl_xor(a0, 2); a1 += __shfl_xor(a1, 2);
    a2 += __shfl_xor(a2, 2); a3 += __shfl_xor(a3, 2);

    const float ig = sigf(a0), fg = sigf(a1), gg = tanh_f(a2), og = sigf(a3);
    c = fg * c + ig * gg;
    hn = og * tanh_f(c);
    if (ks == 0) {
      hbuf[cur ^ 1][jph] = hn;
      if (mode == 0) Y0[(size_t)(b * kL + tt) * kNH + dir * kH + j] = hn;
    }
    __syncthreads();
    zt = znext;
  }
  if (mode == 1 && ks == 0) hfin[b * kH + j] = hn;
}

// ---------------- head (unchanged) ----------------

__global__ __launch_bounds__(256) void head(const float* __restrict__ Y0,
                                            const float* __restrict__ h1b,
                                            const float* __restrict__ Wih1f,
                                            const float* __restrict__ b1f,
                                            const float* __restrict__ xgraph,
                                            const float* __restrict__ Wseq,
                                            const float* __restrict__ bseq,
                                            const float* __restrict__ W1,
                                            const float* __restrict__ b1,
                                            const float* __restrict__ W2,
                                            const float* __restrict__ b2,
                                            float* __restrict__ out) {
  int b = blockIdx.x, t = threadIdx.x;
  __shared__ __align__(16) float x0[kNH];
  __shared__ float gl[512];
  __shared__ __align__(16) float seq[kNH];
  __shared__ __align__(16) float v[512];
  __shared__ __align__(16) float o1[kNH];
  __shared__ float red[512];

  x0[t] = Y0[(size_t)(b * kL) * kNH + t];
  if (t >= kH) seq[t] = h1b[b * kH + (t - kH)];
  __syncthreads();

#pragma unroll
  for (int half = 0; half < 2; half++) {
    int g = t + half * 256;
    const float* wr = Wih1f + (size_t)g * kNH;
    float acc = b1f[g];
#pragma unroll 8
    for (int k = 0; k < kNH; k += 4) {
      float4 xv = *(const float4*)&x0[k];
      float4 wv = *(const float4*)(wr + k);
      acc = fmaf(xv.x, wv.x, acc); acc = fmaf(xv.y, wv.y, acc);
      acc = fmaf(xv.z, wv.z, acc); acc = fmaf(xv.w, wv.w, acc);
    }
    gl[g] = acc;
  }
  __syncthreads();
  if (t < kH) {
    float ig = sigf(gl[t]);
    float gg = tanh_f(gl[2 * kH + t]);
    float og = sigf(gl[3 * kH + t]);
    float c = ig * gg;
    seq[t] = og * tanh_f(c);
  }
  v[t] = xgraph[b * kNH + t];
  __syncthreads();

  {
    float acc = bseq[t];
#pragma unroll 4
    for (int k = 0; k < kNH; k++) acc = fmaf(seq[k], Wseq[(size_t)k * kNH + t], acc);
    v[kNH + t] = (acc > 0.f) ? acc : 0.01f * acc;
  }
  __syncthreads();

  {
    float acc = b1[t];
#pragma unroll 4
    for (int k = 0; k < 512; k++) acc = fmaf(v[k], W1[(size_t)k * kNH + t], acc);
    o1[t] = fmaxf(acc, 0.f);
  }
  __syncthreads();

  red[t]       = o1[t] * W2[t * 2 + 0];
  red[kNH + t] = o1[t] * W2[t * 2 + 1];
  __syncthreads();
  for (int s = 128; s > 0; s >>= 1) {
    if (t < s) { red[t] += red[t + s]; red[kNH + t] += red[kNH + t + s]; }
    __syncthreads();
  }
  if (t == 0) {
    float z0 = red[0] + b2[0], z1 = red[kNH] + b2[1];
    float m = fmaxf(z0, z1);
    float lse = m + logf(__expf(z0 - m) + __expf(z1 - m));
    out[b * 2 + 0] = z0 - lse;
    out[b * 2 + 1] = z1 - lse;
  }
}

}  // namespace

extern "C" void kernel_launch(void* const* d_in, const int* in_sizes, int n_in,
                              void* d_out, int out_size, void* d_ws, size_t ws_size,
                              hipStream_t stream) {
  const float* x     = (const float*)d_in[0];
  const int*   ei    = (const int*)d_in[1];
  const float* Wgcn  = (const float*)d_in[3];
  const float* bgcn  = (const float*)d_in[4];
  const float* l0Wih = (const float*)d_in[5];
  const float* l0Whh = (const float*)d_in[6];
  const float* l0b   = (const float*)d_in[7];
  const float* l1Wih = (const float*)d_in[8];
  const float* l1Whh = (const float*)d_in[9];
  const float* l1b   = (const float*)d_in[10];
  const float* Wseq  = (const float*)d_in[11];
  const float* bseq  = (const float*)d_in[12];
  const float* W1    = (const float*)d_in[13];
  const float* b1    = (const float*)d_in[14];
  const float* W2    = (const float*)d_in[15];
  const float* b2    = (const float*)d_in[16];
  float* out = (float*)d_out;
  char* ws = (char*)d_ws;

  float* Z0     = (float*)(ws);
  float* Y0     = (float*)(ws + 134217728UL);
  float* xgraph = (float*)(ws + 134217728UL + 33554432UL);
  float* h1b    = (float*)(ws + 134217728UL + 33554432UL + 131072UL);
  float* hgcn   = Z0;
  float* xgfull = (float*)(ws + 33554432UL);
  int*   cnt    = (int*)(ws + 67108864UL);
  int*   offs   = (int*)(ws + 67108864UL + 1048576UL);
  int*   cursor = (int*)(ws + 67108864UL + 2097152UL);
  int*   elist  = (int*)(ws + 67108864UL + 3145728UL);
  float* dinv   = (float*)(ws + 67108864UL + 6291456UL);
  float* Z1b    = Z0;

  unsigned short* gWhi = (unsigned short*)(ws + 78643200UL);
  unsigned short* gWlo = (unsigned short*)(ws + 78643200UL + 393216UL);
  unsigned short* l0hi = (unsigned short*)(ws + 134217728UL);
  unsigned short* l0lo = (unsigned short*)(ws + 134217728UL + 1572864UL);
  unsigned short* l1hi = (unsigned short*)(ws + 104857600UL);
  unsigned short* l1lo = (unsigned short*)(ws + 104857600UL + 262144UL);

  const int* erow = ei;
  const int* ecol = ei + kE;

  // ---- GCN path ----
  hipMemsetAsync(cnt, 0, kN * sizeof(int), stream);
  count_edges<<<kE / 256, 256, 0, stream>>>(ecol, cnt);
  scan_dinv<<<1, 1024, 0, stream>>>(cnt, offs, cursor, dinv);
  fill_csr<<<kE / 256, 256, 0, stream>>>(erow, ecol, cursor, elist);
  convert_bt<<<(kNH * kF + 255) / 256, 256, 0, stream>>>(Wgcn, gWhi, gWlo, kNH, kF, 1);
  gemm3<<<dim3(kNH / 128, kN / 128), 256, 0, stream>>>(x, gWhi, gWlo, hgcn, kN, kNH, kF);
  gcn_gather<<<kN, 256, 0, stream>>>(hgcn, offs, elist, dinv, bgcn, xgfull);
  segmax<<<kB, 256, 0, stream>>>(xgfull, xgraph);

  // ---- LSTM path ----
  convert_bt<<<(1024 * kF + 255) / 256, 256, 0, stream>>>(l0Wih, l0hi, l0lo, 1024, kF, 0);
  gemm3<<<dim3(1024 / 128, kN / 128), 256, 0, stream>>>(x, l0hi, l0lo, Z0, kN, 1024, kF);
  lstm_rec<<<256, 512, 0, stream>>>(Z0, 1024, l0Whh, l0b, Y0, nullptr, 0);
  convert_bt<<<(512 * kNH + 255) / 256, 256, 0, stream>>>(l1Wih + 512 * 256, l1hi, l1lo,
                                                          512, kNH, 0);
  gemm3<<<dim3(512 / 128, kN / 128), 256, 0, stream>>>(Y0, l1hi, l1lo, Z1b, kN, 512, kNH);
  lstm_rec<<<128, 512, 0, stream>>>(Z1b, 512, l1Whh, l1b, nullptr, h1b, 1);

  // ---- head ----
  head<<<kB, 256, 0, stream>>>(Y0, h1b, l1Wih, l1b, xgraph, Wseq, bseq, W1, b1, W2, b2, out);
}

// Round 6
// 1125.131 us; speedup vs baseline: 1.0588x; 1.0588x over previous
//
#include <hip/hip_runtime.h>
#include <math.h>

// Model_13486197309850: GCN(+self-loop sym-norm, segment_max) || 2-layer BiLSTM -> MLP head.
// R5->R6: lstm_rec weights as 32 NAMED float4 variables (no array, no asm pins).
//   r2/r3/r5 all showed VGPR=80-88: SROA refuses to scalarize the 512B weight alloca
//   (and r3/r5's per-element asm pins pinned the alloca in memory), so weights lived in
//   scratch and each step re-read 512B/thread from private mem. Named values are SSA from
//   birth -> allocator keeps them in VGPRs (pressure ~160 < 256 cap at 2 waves/SIMD).
//   Rotated hbuf layout kept (r5 proved conflicts -> 0).
// GEMMs (bf16 MFMA 3-term hi/lo split) unchanged from r2.

namespace {

constexpr int kN  = 32768;
constexpr int kB  = 128;
constexpr int kL  = 256;
constexpr int kF  = 768;
constexpr int kNH = 256;
constexpr int kH  = 128;
constexpr int kE  = 524288;

typedef __attribute__((ext_vector_type(8))) short bf16x8;
typedef __attribute__((ext_vector_type(4))) float f32x4;
typedef __attribute__((address_space(3))) unsigned int lds_u32;
typedef __attribute__((address_space(1))) unsigned int glb_u32;

__device__ __forceinline__ float sigf(float x)  { return 1.f / (1.f + __expf(-x)); }
__device__ __forceinline__ float tanh_f(float x){ return 1.f - 2.f / (1.f + __expf(2.f * x)); }

__device__ __forceinline__ unsigned short f2bf(float f) {
  unsigned int u = __float_as_uint(f);
  u = u + 0x7fffu + ((u >> 16) & 1u);   // RNE to bf16
  return (unsigned short)(u >> 16);
}
__device__ __forceinline__ float bf2f(unsigned short h) {
  return __uint_as_float((unsigned int)h << 16);
}

// ---------------- GCN: degree count / scan / CSR fill ----------------

__global__ void count_edges(const int* __restrict__ col, int* __restrict__ cnt) {
  int e = blockIdx.x * 256 + threadIdx.x;
  if (e < kE) atomicAdd(&cnt[col[e]], 1);
}

__global__ void scan_dinv(const int* __restrict__ cnt, int* __restrict__ offs,
                          int* __restrict__ cursor, float* __restrict__ dinv) {
  __shared__ int part[1024];
  int t = threadIdx.x;
  int base = t * 32;
  int loc[32];
  int s = 0;
#pragma unroll
  for (int i = 0; i < 32; i++) { loc[i] = cnt[base + i]; s += loc[i]; }
  part[t] = s;
  __syncthreads();
  for (int d = 1; d < 1024; d <<= 1) {
    int v = part[t];
    int add = (t >= d) ? part[t - d] : 0;
    __syncthreads();
    part[t] = v + add;
    __syncthreads();
  }
  int run = (t == 0) ? 0 : part[t - 1];
#pragma unroll
  for (int i = 0; i < 32; i++) {
    offs[base + i] = run;
    cursor[base + i] = run;
    dinv[base + i] = rsqrtf((float)(loc[i] + 1));
    run += loc[i];
  }
  if (t == 1023) offs[kN] = run;
}

__global__ void fill_csr(const int* __restrict__ row, const int* __restrict__ col,
                         int* __restrict__ cursor, int* __restrict__ elist) {
  int e = blockIdx.x * 256 + threadIdx.x;
  if (e < kE) {
    int c = col[e];
    int p = atomicAdd(&cursor[c], 1);
    elist[p] = row[e];
  }
}

// ---------------- weight conversion: fp32 -> (N,K) bf16 hi/lo ----------------

__global__ void convert_bt(const float* __restrict__ W, unsigned short* __restrict__ hi,
                           unsigned short* __restrict__ lo, int Nn, int Kk, int trans) {
  int idx = blockIdx.x * 256 + threadIdx.x;
  if (idx >= Nn * Kk) return;
  int n = idx / Kk, k = idx - n * Kk;
  float f = trans ? W[(size_t)k * Nn + n] : W[idx];
  unsigned short h = f2bf(f);
  hi[idx] = h;
  lo[idx] = f2bf(f - bf2f(h));
}

// ---------------- MFMA GEMM, 3-term hi/lo split (unchanged from r2) ----------------

__global__ __launch_bounds__(256, 2) void gemm3(const float* __restrict__ A,
                                                const unsigned short* __restrict__ Bhi,
                                                const unsigned short* __restrict__ Blo,
                                                float* __restrict__ C,
                                                int M, int N, int K) {
  __shared__ __align__(16) char lds[32768];
  const int tid = threadIdx.x;
  const int lane = tid & 63;
  const int w = tid >> 6, wr = w >> 1, wc = w & 1;
  const int m0 = blockIdx.y * 128, n0 = blockIdx.x * 128;

  f32x4 acc[4][4];
#pragma unroll
  for (int i = 0; i < 4; i++)
#pragma unroll
    for (int j = 0; j < 4; j++) acc[i][j] = (f32x4)0.f;

  const float* aptr[4];
  int aoff[4];
#pragma unroll
  for (int i = 0; i < 4; i++) {
    int f = tid + i * 256;
    int row = f >> 3, kq4 = f & 7;
    aptr[i] = A + (size_t)(m0 + row) * K + kq4 * 4;
    int sub = row >> 4, r = row & 15, q = kq4 >> 1, hs = kq4 & 1;
    aoff[i] = sub * 1024 + (q * 16 + r) * 16 + hs * 8;
  }
  const unsigned short* bsrc[4];
  int boff[4];
#pragma unroll
  for (int j = 0; j < 4; j++) {
    int id = w * 4 + j;
    int isLo = id >> 3, sub = id & 7;
    const unsigned short* Bp = isLo ? Blo : Bhi;
    bsrc[j] = Bp + (size_t)(n0 + sub * 16 + (lane & 15)) * K + (lane >> 4) * 8;
    boff[j] = 16384 + isLo * 8192 + sub * 1024;
  }

  for (int k0 = 0; k0 < K; k0 += 32) {
#pragma unroll
    for (int j = 0; j < 4; j++) {
      __builtin_amdgcn_global_load_lds((const glb_u32*)bsrc[j],
                                       (lds_u32*)(lds + boff[j]), 16, 0, 0);
      bsrc[j] += 32;
    }
#pragma unroll
    for (int i = 0; i < 4; i++) {
      f32x4 v = *(const f32x4*)(aptr[i]);
      aptr[i] += 32;
      unsigned short h0 = f2bf(v.x), h1 = f2bf(v.y), h2 = f2bf(v.z), h3 = f2bf(v.w);
      unsigned short g0 = f2bf(v.x - bf2f(h0)), g1 = f2bf(v.y - bf2f(h1));
      unsigned short g2 = f2bf(v.z - bf2f(h2)), g3 = f2bf(v.w - bf2f(h3));
      uint2 hv, lv;
      hv.x = (unsigned int)h0 | ((unsigned int)h1 << 16);
      hv.y = (unsigned int)h2 | ((unsigned int)h3 << 16);
      lv.x = (unsigned int)g0 | ((unsigned int)g1 << 16);
      lv.y = (unsigned int)g2 | ((unsigned int)g3 << 16);
      *(uint2*)(lds + aoff[i]) = hv;
      *(uint2*)(lds + aoff[i] + 8192) = lv;
    }
    __syncthreads();

    const bf16x8* L = (const bf16x8*)lds;
    bf16x8 ah[4], al[4], bh[4], bl[4];
#pragma unroll
    for (int m = 0; m < 4; m++) {
      ah[m] = L[(wr * 4 + m) * 64 + lane];
      al[m] = L[512 + (wr * 4 + m) * 64 + lane];
    }
#pragma unroll
    for (int n = 0; n < 4; n++) {
      bh[n] = L[1024 + (wc * 4 + n) * 64 + lane];
      bl[n] = L[1536 + (wc * 4 + n) * 64 + lane];
    }
#pragma unroll
    for (int m = 0; m < 4; m++)
#pragma unroll
      for (int n = 0; n < 4; n++) {
        acc[m][n] = __builtin_amdgcn_mfma_f32_16x16x32_bf16(ah[m], bh[n], acc[m][n], 0, 0, 0);
        acc[m][n] = __builtin_amdgcn_mfma_f32_16x16x32_bf16(ah[m], bl[n], acc[m][n], 0, 0, 0);
        acc[m][n] = __builtin_amdgcn_mfma_f32_16x16x32_bf16(al[m], bh[n], acc[m][n], 0, 0, 0);
      }
    __syncthreads();
  }

#pragma unroll
  for (int m = 0; m < 4; m++)
#pragma unroll
    for (int n = 0; n < 4; n++) {
      int r0 = m0 + wr * 64 + m * 16 + (lane >> 4) * 4;
      int cc = n0 + wc * 64 + n * 16 + (lane & 15);
#pragma unroll
      for (int j = 0; j < 4; j++)
        C[(size_t)(r0 + j) * N + cc] = acc[m][n][j];
    }
}

// ---------------- GCN gather + relu(+bias), then segment max ----------------

__global__ __launch_bounds__(256) void gcn_gather(const float* __restrict__ hg,
                                                  const int* __restrict__ offs,
                                                  const int* __restrict__ elist,
                                                  const float* __restrict__ dinv,
                                                  const float* __restrict__ bgcn,
                                                  float* __restrict__ out) {
  int n = blockIdx.x, j = threadIdx.x;
  float di = dinv[n];
  float acc = hg[(size_t)n * kNH + j] * (di * di);
  int s = offs[n], e = offs[n + 1];
  int p = s;
  for (; p + 4 <= e; p += 4) {
    int r0 = elist[p], r1 = elist[p + 1], r2 = elist[p + 2], r3 = elist[p + 3];
    float w0 = di * dinv[r0], w1 = di * dinv[r1], w2 = di * dinv[r2], w3 = di * dinv[r3];
    float v0 = hg[(size_t)r0 * kNH + j], v1 = hg[(size_t)r1 * kNH + j];
    float v2 = hg[(size_t)r2 * kNH + j], v3 = hg[(size_t)r3 * kNH + j];
    acc = fmaf(v0, w0, acc); acc = fmaf(v1, w1, acc);
    acc = fmaf(v2, w2, acc); acc = fmaf(v3, w3, acc);
  }
  for (; p < e; p++) {
    int r = elist[p];
    acc = fmaf(hg[(size_t)r * kNH + j], di * dinv[r], acc);
  }
  acc += bgcn[j];
  out[(size_t)n * kNH + j] = fmaxf(acc, 0.f);
}

__global__ __launch_bounds__(256) void segmax(const float* __restrict__ xg_full,
                                              float* __restrict__ x_graph) {
  int g = blockIdx.x, j = threadIdx.x;
  const float* base = xg_full + (size_t)g * kL * kNH + j;
  float m0 = -1e30f, m1 = -1e30f, m2 = -1e30f, m3 = -1e30f;
  for (int t = 0; t < kL; t += 4) {
    m0 = fmaxf(m0, base[(size_t)(t + 0) * kNH]);
    m1 = fmaxf(m1, base[(size_t)(t + 1) * kNH]);
    m2 = fmaxf(m2, base[(size_t)(t + 2) * kNH]);
    m3 = fmaxf(m3, base[(size_t)(t + 3) * kNH]);
  }
  x_graph[g * kNH + j] = fmaxf(fmaxf(m0, m1), fmaxf(m2, m3));
}

// ---------------- LSTM recurrence: quad k-split, NAMED weight registers ----------------
// 512 threads: j = t>>2 (h-unit), ks = t&3 (k-slice of 32).
// Weights: 32 named float4 (4 gates x 8 groups) -- no array, no asm, pure SSA.
// hbuf rotated: logical group g of slice ks at phys float4 ks*8+((g+ks)&7) (conflict-free,
// verified r5: SQ_LDS_BANK_CONFLICT -> 0).

#define LDW(q) \
  float4 w##q##0, w##q##1, w##q##2, w##q##3, w##q##4, w##q##5, w##q##6, w##q##7; \
  { const float4* wp = (const float4*)(wb + (q) * 16384); \
    w##q##0 = wp[0]; w##q##1 = wp[1]; w##q##2 = wp[2]; w##q##3 = wp[3]; \
    w##q##4 = wp[4]; w##q##5 = wp[5]; w##q##6 = wp[6]; w##q##7 = wp[7]; }

#define FMA4(q, wv, hv) \
  a##q = fmaf(wv.x, hv.x, a##q); a##q = fmaf(wv.y, hv.y, a##q); \
  a##q = fmaf(wv.z, hv.z, a##q); a##q = fmaf(wv.w, hv.w, a##q)

#define STEPP(p) { \
  float4 h4 = hb[ks * 8 + ((p + ks) & 7)]; \
  FMA4(0, w0##p, h4); FMA4(1, w1##p, h4); FMA4(2, w2##p, h4); FMA4(3, w3##p, h4); }

__global__ __launch_bounds__(512, 1) void lstm_rec(const float* __restrict__ Z, int zstride,
                                                   const float* __restrict__ Whh2,
                                                   const float* __restrict__ bias2,
                                                   float* __restrict__ Y0,
                                                   float* __restrict__ hfin, int mode) {
  __shared__ __align__(16) float hbuf[2][kH];
  int b, dir;
  if (mode == 0) { dir = blockIdx.x >> 7; b = blockIdx.x & 127; }
  else           { dir = 1;               b = blockIdx.x; }
  const bool rev = (dir == 1);
  const int t0 = threadIdx.x;
  const int j = t0 >> 2;
  const int ks = t0 & 3;

  const float* wb = Whh2 + (size_t)dir * 65536 + (size_t)j * kH + ks * 32;
  LDW(0) LDW(1) LDW(2) LDW(3)

  const float bg = bias2[dir * 512 + ks * kH + j];
  const int zcol = (mode == 0) ? dir * 512 : 0;
  float c = 0.f, hn = 0.f;

  // phys index of logical h[j] (for the single-float state writes)
  const int jph = ((j >> 5) * 8 + ((((j >> 2) & 7) + (j >> 5)) & 7)) * 4 + (j & 3);

  if (t0 < kH) hbuf[0][t0] = 0.f;  // all-zero: layout-agnostic

  const float* zp = Z + (size_t)(b * kL + (rev ? kL - 1 : 0)) * zstride + zcol + ks * kH + j;
  const long zinc = rev ? -(long)zstride : (long)zstride;
  float zt = *zp;
  __syncthreads();

  for (int t = 0; t < kL; t++) {
    const int tt = rev ? (kL - 1 - t) : t;
    float znext = 0.f;
    if (t < kL - 1) znext = zp[zinc];
    zp += zinc;
    const int cur = t & 1;

    const float4* hb = (const float4*)hbuf[cur];
    float a0 = 0.f, a1 = 0.f, a2 = 0.f, a3 = 0.f;
    STEPP(0) STEPP(1) STEPP(2) STEPP(3) STEPP(4) STEPP(5) STEPP(6) STEPP(7)

    const float zb = zt + bg;
    a0 += (ks == 0) ? zb : 0.f;
    a1 += (ks == 1) ? zb : 0.f;
    a2 += (ks == 2) ? zb : 0.f;
    a3 += (ks == 3) ? zb : 0.f;
    a0 += __shfl_xor(a0, 1); a1 += __shfl_xor(a1, 1);
    a2 += __shfl_xor(a2, 1); a3 += __shfl_xor(a3, 1);
    a0 += __shfl_xor(a0, 2); a1 += __shfl_xor(a1, 2);
    a2 += __shfl_xor(a2, 2); a3 += __shfl_xor(a3, 2);

    const float ig = sigf(a0), fg = sigf(a1), gg = tanh_f(a2), og = sigf(a3);
    c = fg * c + ig * gg;
    hn = og * tanh_f(c);
    if (ks == 0) {
      hbuf[cur ^ 1][jph] = hn;
      if (mode == 0) Y0[(size_t)(b * kL + tt) * kNH + dir * kH + j] = hn;
    }
    __syncthreads();
    zt = znext;
  }
  if (mode == 1 && ks == 0) hfin[b * kH + j] = hn;
}

#undef LDW
#undef FMA4
#undef STEPP

// ---------------- head (unchanged) ----------------

__global__ __launch_bounds__(256) void head(const float* __restrict__ Y0,
                                            const float* __restrict__ h1b,
                                            const float* __restrict__ Wih1f,
                                            const float* __restrict__ b1f,
                                            const float* __restrict__ xgraph,
                                            const float* __restrict__ Wseq,
                                            const float* __restrict__ bseq,
                                            const float* __restrict__ W1,
                                            const float* __restrict__ b1,
                                            const float* __restrict__ W2,
                                            const float* __restrict__ b2,
                                            float* __restrict__ out) {
  int b = blockIdx.x, t = threadIdx.x;
  __shared__ __align__(16) float x0[kNH];
  __shared__ float gl[512];
  __shared__ __align__(16) float seq[kNH];
  __shared__ __align__(16) float v[512];
  __shared__ __align__(16) float o1[kNH];
  __shared__ float red[512];

  x0[t] = Y0[(size_t)(b * kL) * kNH + t];
  if (t >= kH) seq[t] = h1b[b * kH + (t - kH)];
  __syncthreads();

#pragma unroll
  for (int half = 0; half < 2; half++) {
    int g = t + half * 256;
    const float* wr = Wih1f + (size_t)g * kNH;
    float acc = b1f[g];
#pragma unroll 8
    for (int k = 0; k < kNH; k += 4) {
      float4 xv = *(const float4*)&x0[k];
      float4 wv = *(const float4*)(wr + k);
      acc = fmaf(xv.x, wv.x, acc); acc = fmaf(xv.y, wv.y, acc);
      acc = fmaf(xv.z, wv.z, acc); acc = fmaf(xv.w, wv.w, acc);
    }
    gl[g] = acc;
  }
  __syncthreads();
  if (t < kH) {
    float ig = sigf(gl[t]);
    float gg = tanh_f(gl[2 * kH + t]);
    float og = sigf(gl[3 * kH + t]);
    float c = ig * gg;
    seq[t] = og * tanh_f(c);
  }
  v[t] = xgraph[b * kNH + t];
  __syncthreads();

  {
    float acc = bseq[t];
#pragma unroll 4
    for (int k = 0; k < kNH; k++) acc = fmaf(seq[k], Wseq[(size_t)k * kNH + t], acc);
    v[kNH + t] = (acc > 0.f) ? acc : 0.01f * acc;
  }
  __syncthreads();

  {
    float acc = b1[t];
#pragma unroll 4
    for (int k = 0; k < 512; k++) acc = fmaf(v[k], W1[(size_t)k * kNH + t], acc);
    o1[t] = fmaxf(acc, 0.f);
  }
  __syncthreads();

  red[t]       = o1[t] * W2[t * 2 + 0];
  red[kNH + t] = o1[t] * W2[t * 2 + 1];
  __syncthreads();
  for (int s = 128; s > 0; s >>= 1) {
    if (t < s) { red[t] += red[t + s]; red[kNH + t] += red[kNH + t + s]; }
    __syncthreads();
  }
  if (t == 0) {
    float z0 = red[0] + b2[0], z1 = red[kNH] + b2[1];
    float m = fmaxf(z0, z1);
    float lse = m + logf(__expf(z0 - m) + __expf(z1 - m));
    out[b * 2 + 0] = z0 - lse;
    out[b * 2 + 1] = z1 - lse;
  }
}

}  // namespace

extern "C" void kernel_launch(void* const* d_in, const int* in_sizes, int n_in,
                              void* d_out, int out_size, void* d_ws, size_t ws_size,
                              hipStream_t stream) {
  const float* x     = (const float*)d_in[0];
  const int*   ei    = (const int*)d_in[1];
  const float* Wgcn  = (const float*)d_in[3];
  const float* bgcn  = (const float*)d_in[4];
  const float* l0Wih = (const float*)d_in[5];
  const float* l0Whh = (const float*)d_in[6];
  const float* l0b   = (const float*)d_in[7];
  const float* l1Wih = (const float*)d_in[8];
  const float* l1Whh = (const float*)d_in[9];
  const float* l1b   = (const float*)d_in[10];
  const float* Wseq  = (const float*)d_in[11];
  const float* bseq  = (const float*)d_in[12];
  const float* W1    = (const float*)d_in[13];
  const float* b1    = (const float*)d_in[14];
  const float* W2    = (const float*)d_in[15];
  const float* b2    = (const float*)d_in[16];
  float* out = (float*)d_out;
  char* ws = (char*)d_ws;

  float* Z0     = (float*)(ws);
  float* Y0     = (float*)(ws + 134217728UL);
  float* xgraph = (float*)(ws + 134217728UL + 33554432UL);
  float* h1b    = (float*)(ws + 134217728UL + 33554432UL + 131072UL);
  float* hgcn   = Z0;
  float* xgfull = (float*)(ws + 33554432UL);
  int*   cnt    = (int*)(ws + 67108864UL);
  int*   offs   = (int*)(ws + 67108864UL + 1048576UL);
  int*   cursor = (int*)(ws + 67108864UL + 2097152UL);
  int*   elist  = (int*)(ws + 67108864UL + 3145728UL);
  float* dinv   = (float*)(ws + 67108864UL + 6291456UL);
  float* Z1b    = Z0;

  unsigned short* gWhi = (unsigned short*)(ws + 78643200UL);
  unsigned short* gWlo = (unsigned short*)(ws + 78643200UL + 393216UL);
  unsigned short* l0hi = (unsigned short*)(ws + 134217728UL);
  unsigned short* l0lo = (unsigned short*)(ws + 134217728UL + 1572864UL);
  unsigned short* l1hi = (unsigned short*)(ws + 104857600UL);
  unsigned short* l1lo = (unsigned short*)(ws + 104857600UL + 262144UL);

  const int* erow = ei;
  const int* ecol = ei + kE;

  // ---- GCN path ----
  hipMemsetAsync(cnt, 0, kN * sizeof(int), stream);
  count_edges<<<kE / 256, 256, 0, stream>>>(ecol, cnt);
  scan_dinv<<<1, 1024, 0, stream>>>(cnt, offs, cursor, dinv);
  fill_csr<<<kE / 256, 256, 0, stream>>>(erow, ecol, cursor, elist);
  convert_bt<<<(kNH * kF + 255) / 256, 256, 0, stream>>>(Wgcn, gWhi, gWlo, kNH, kF, 1);
  gemm3<<<dim3(kNH / 128, kN / 128), 256, 0, stream>>>(x, gWhi, gWlo, hgcn, kN, kNH, kF);
  gcn_gather<<<kN, 256, 0, stream>>>(hgcn, offs, elist, dinv, bgcn, xgfull);
  segmax<<<kB, 256, 0, stream>>>(xgfull, xgraph);

  // ---- LSTM path ----
  convert_bt<<<(1024 * kF + 255) / 256, 256, 0, stream>>>(l0Wih, l0hi, l0lo, 1024, kF, 0);
  gemm3<<<dim3(1024 / 128, kN / 128), 256, 0, stream>>>(x, l0hi, l0lo, Z0, kN, 1024, kF);
  lstm_rec<<<256, 512, 0, stream>>>(Z0, 1024, l0Whh, l0b, Y0, nullptr, 0);
  convert_bt<<<(512 * kNH + 255) / 256, 256, 0, stream>>>(l1Wih + 512 * 256, l1hi, l1lo,
                                                          512, kNH, 0);
  gemm3<<<dim3(512 / 128, kN / 128), 256, 0, stream>>>(Y0, l1hi, l1lo, Z1b, kN, 512, kNH);
  lstm_rec<<<128, 512, 0, stream>>>(Z1b, 512, l1Whh, l1b, nullptr, h1b, 1);

  // ---- head ----
  head<<<kB, 256, 0, stream>>>(Y0, h1b, l1Wih, l1b, xgraph, Wseq, bseq, W1, b1, W2, b2, out);
}